// Round 1
// baseline (308.731 us; speedup 1.0000x reference)
//
#include <hip/hip_runtime.h>

#define NB 2048
#define NU 512
#define NL 32
#define NH 64
#define RT 64            // rows per decoder block
#define PAD 4            // hT stride = RT+PAD = 68 floats (16B-aligned, conflict-free)

typedef float f4 __attribute__((ext_vector_type(4)));

// ---------------------------------------------------------------- encoder ---
// grid: 256 blocks x 256 threads, 8 rows per block
__global__ __launch_bounds__(256)
void enc_kernel(const float* __restrict__ x,
                const float* __restrict__ We1, const float* __restrict__ be1,
                const float* __restrict__ We2, const float* __restrict__ be2,
                const float* __restrict__ We3, const float* __restrict__ be3,
                const float* __restrict__ We4, const float* __restrict__ be4,
                float* __restrict__ z)
{
    const int RE = 8;
    __shared__ float xs[RE][512];     // 16 KB
    __shared__ float ws[128 * 64];    // 32 KB chunk of We1
    __shared__ float h[RE][NH];       // 2 KB
    __shared__ float h2s[RE][NH];     // 2 KB

    const int t  = threadIdx.x;
    const int r0 = blockIdx.x * RE;

    // stage x tile (contiguous 8*512 floats)
    {
        const f4* xv  = (const f4*)(x + (size_t)r0 * 512);
        f4*       xsv = (f4*)&xs[0][0];
        for (int i = t; i < RE * 512 / 4; i += 256) xsv[i] = xv[i];
    }

    const int j = t & 63;     // output column
    const int w = t >> 6;     // wave id -> rows w and w+4

    // ---- layer 1: K=512, chunked We1 through LDS ----
    float acc0 = be1[j], acc1 = be1[j];
    for (int kc = 0; kc < 512; kc += 128) {
        __syncthreads();  // protect ws reuse (also covers xs staging on iter 0... see below)
        const f4* wv  = (const f4*)(We1 + (size_t)kc * 64);
        f4*       wsv = (f4*)ws;
        for (int i = t; i < 128 * 64 / 4; i += 256) wsv[i] = wv[i];
        __syncthreads();  // ws (and xs, first iter) ready
        #pragma unroll 8
        for (int k = 0; k < 128; ++k) {
            float wval = ws[k * 64 + j];
            acc0 = fmaf(xs[w][kc + k],     wval, acc0);
            acc1 = fmaf(xs[w + 4][kc + k], wval, acc1);
        }
    }
    acc0 = fmaxf(acc0, 0.f); acc1 = fmaxf(acc1, 0.f);
    __syncthreads();
    h[w][j] = acc0; h[w + 4][j] = acc1;
    __syncthreads();

    // ---- layer 2: K=64 ----
    acc0 = be2[j]; acc1 = be2[j];
    #pragma unroll
    for (int k = 0; k < 64; ++k) {
        float wval = We2[k * 64 + j];
        acc0 = fmaf(h[w][k],     wval, acc0);
        acc1 = fmaf(h[w + 4][k], wval, acc1);
    }
    acc0 = fmaxf(acc0, 0.f); acc1 = fmaxf(acc1, 0.f);
    h2s[w][j] = acc0; h2s[w + 4][j] = acc1;
    __syncthreads();

    // ---- layer 3: K=64 ----
    acc0 = be3[j]; acc1 = be3[j];
    #pragma unroll
    for (int k = 0; k < 64; ++k) {
        float wval = We3[k * 64 + j];
        acc0 = fmaf(h2s[w][k],     wval, acc0);
        acc1 = fmaf(h2s[w + 4][k], wval, acc1);
    }
    acc0 = fmaxf(acc0, 0.f); acc1 = fmaxf(acc1, 0.f);
    h[w][j] = acc0; h[w + 4][j] = acc1;
    __syncthreads();

    // ---- layer 4: K=64 -> 32 outputs, no relu ----
    const int j4  = t & 31;
    const int row = t >> 5;
    float acc = be4[j4];
    #pragma unroll
    for (int k = 0; k < 64; ++k)
        acc = fmaf(h[row][k], We4[k * 32 + j4], acc);
    z[(size_t)r0 * 32 + t] = acc;   // flat index == row*32 + j4, coalesced
}

// ---------------------------------------------------------------- decoder ---
template <int K>
__device__ __forceinline__ void gemm_tile(const float (*hIn)[RT + PAD],
                                          const float* __restrict__ w,
                                          const float* __restrict__ bias,
                                          int rr0, int c0, float acc[4][4])
{
    #pragma unroll
    for (int i = 0; i < 4; ++i) {
        float bv = bias[c0 + i];
        acc[0][i] = bv; acc[1][i] = bv; acc[2][i] = bv; acc[3][i] = bv;
    }
    #pragma unroll 4
    for (int k = 0; k < K; ++k) {
        f4 a = *(const f4*)&hIn[k][rr0];
        f4 b = *(const f4*)&w[k * NH + c0];
        #pragma unroll
        for (int r = 0; r < 4; ++r)
            #pragma unroll
            for (int c = 0; c < 4; ++c)
                acc[r][c] = fmaf(a[r], b[c], acc[r][c]);
    }
}

__device__ __forceinline__ void store_relu_T(float acc[4][4],
                                             float (*hOut)[RT + PAD],
                                             int rr0, int c0)
{
    #pragma unroll
    for (int c = 0; c < 4; ++c) {
        f4 v;
        v[0] = fmaxf(acc[0][c], 0.f);
        v[1] = fmaxf(acc[1][c], 0.f);
        v[2] = fmaxf(acc[2][c], 0.f);
        v[3] = fmaxf(acc[3][c], 0.f);
        *(f4*)&hOut[c0 + c][rr0] = v;
    }
}

// grid: 512 units * 32 row-tiles = 16384 blocks x 256 threads
__global__ __launch_bounds__(256, 3)
void dec_kernel(const float* __restrict__ z,
                const float* __restrict__ Wd1, const float* __restrict__ bd1,
                const float* __restrict__ Wd2, const float* __restrict__ bd2,
                const float* __restrict__ Wd3, const float* __restrict__ bd3,
                const float* __restrict__ Wd4, const float* __restrict__ bd4,
                float* __restrict__ out)
{
    __shared__ float wb[NH * NH];        // 16 KB, ping buffer for W of current layer
    __shared__ float w4s[NH];
    __shared__ float bs1[NH], bs2[NH], bs3[NH];
    __shared__ float hA[NH][RT + PAD];   // 17.4 KB, activations^T [k][row]
    __shared__ float hB[NH][RT + PAD];

    const int nwg = gridDim.x;
    const int bid = blockIdx.x;
    // XCD-bijective swizzle: 16384 % 8 == 0, contiguous wg chunk per XCD
    const int wg  = (bid & 7) * (nwg >> 3) + (bid >> 3);
    const int u   = wg >> 5;            // unit
    const int r0  = (wg & 31) * RT;     // row tile

    const int t = threadIdx.x;

    // stage Wd1[u] + all biases + Wd4[u] + transposed z tile
    {
        const f4* s1 = (const f4*)(Wd1 + (size_t)u * NL * NH);
        f4* d1 = (f4*)wb;
        for (int i = t; i < NL * NH / 4; i += 256) d1[i] = s1[i];
        if (t < 16)              ((f4*)w4s)[t]      = ((const f4*)(Wd4 + (size_t)u * NH))[t];
        else if (t < 32)         ((f4*)bs1)[t - 16] = ((const f4*)(bd1 + (size_t)u * NH))[t - 16];
        else if (t < 48)         ((f4*)bs2)[t - 32] = ((const f4*)(bd2 + (size_t)u * NH))[t - 32];
        else if (t < 64)         ((f4*)bs3)[t - 48] = ((const f4*)(bd3 + (size_t)u * NH))[t - 48];

        const f4* zv = (const f4*)(z + (size_t)r0 * NL);
        for (int i = t; i < RT * NL / 4; i += 256) {
            f4 v = zv[i];
            int r  = i >> 3;          // row within tile
            int c4 = (i & 7) * 4;     // latent col group
            hA[c4 + 0][r] = v[0];
            hA[c4 + 1][r] = v[1];
            hA[c4 + 2][r] = v[2];
            hA[c4 + 3][r] = v[3];
        }
    }
    __syncthreads();

    const int tc  = t & 15;
    const int tr  = t >> 4;
    const int c0  = tc * 4;
    const int rr0 = tr * 4;

    float acc[4][4];

    // layer 1: zT(hA, K=32) @ Wd1 -> hB
    gemm_tile<NL>(hA, wb, bs1, rr0, c0, acc);
    store_relu_T(acc, hB, rr0, c0);
    __syncthreads();

    // load Wd2 into wb (safe: everyone past GEMM1)
    {
        const f4* s2 = (const f4*)(Wd2 + (size_t)u * NH * NH);
        f4* d = (f4*)wb;
        for (int i = t; i < NH * NH / 4; i += 256) d[i] = s2[i];
    }
    __syncthreads();

    // layer 2: hB (K=64) @ Wd2 -> hA
    gemm_tile<NH>(hB, wb, bs2, rr0, c0, acc);
    store_relu_T(acc, hA, rr0, c0);
    __syncthreads();

    // load Wd3
    {
        const f4* s3 = (const f4*)(Wd3 + (size_t)u * NH * NH);
        f4* d = (f4*)wb;
        for (int i = t; i < NH * NH / 4; i += 256) d[i] = s3[i];
    }
    __syncthreads();

    // layer 3 + final dot: hA (K=64) @ Wd3 -> relu -> dot Wd4
    gemm_tile<NH>(hA, wb, bs3, rr0, c0, acc);

    float part[4];
    #pragma unroll
    for (int r = 0; r < 4; ++r) {
        part[r] = 0.f;
        #pragma unroll
        for (int c = 0; c < 4; ++c)
            part[r] += fmaxf(acc[r][c], 0.f) * w4s[c0 + c];
    }
    // reduce across the 16 column-lanes (lane bits 0..3)
    #pragma unroll
    for (int m = 1; m <= 8; m <<= 1) {
        #pragma unroll
        for (int r = 0; r < 4; ++r)
            part[r] += __shfl_xor(part[r], m, 64);
    }
    if (tc == 0) {
        const float b4 = bd4[u];
        #pragma unroll
        for (int r = 0; r < 4; ++r)
            out[(size_t)(r0 + rr0 + r) * NU + u] = part[r] + b4;
    }
}

// ----------------------------------------------------------------- launch ---
extern "C" void kernel_launch(void* const* d_in, const int* in_sizes, int n_in,
                              void* d_out, int out_size, void* d_ws, size_t ws_size,
                              hipStream_t stream)
{
    const float* x   = (const float*)d_in[0];
    const float* We1 = (const float*)d_in[1];
    const float* be1 = (const float*)d_in[2];
    const float* We2 = (const float*)d_in[3];
    const float* be2 = (const float*)d_in[4];
    const float* We3 = (const float*)d_in[5];
    const float* be3 = (const float*)d_in[6];
    const float* We4 = (const float*)d_in[7];
    const float* be4 = (const float*)d_in[8];
    const float* Wd1 = (const float*)d_in[9];
    const float* bd1 = (const float*)d_in[10];
    const float* Wd2 = (const float*)d_in[11];
    const float* bd2 = (const float*)d_in[12];
    const float* Wd3 = (const float*)d_in[13];
    const float* bd3 = (const float*)d_in[14];
    const float* Wd4 = (const float*)d_in[15];
    const float* bd4 = (const float*)d_in[16];
    float* out = (float*)d_out;

    float* z = (float*)d_ws;   // needs NB*NL*4 = 256 KB scratch

    enc_kernel<<<NB / 8, 256, 0, stream>>>(x, We1, be1, We2, be2, We3, be3,
                                           We4, be4, z);
    dec_kernel<<<NU * (NB / RT), 256, 0, stream>>>(z, Wd1, bd1, Wd2, bd2,
                                                   Wd3, bd3, Wd4, bd4, out);
}

// Round 2
// 110.606 us; speedup vs baseline: 2.7913x; 2.7913x over previous
//
#include <hip/hip_runtime.h>
#include <hip/hip_bf16.h>
#include <stdint.h>

#define NB 2048
#define NU 512
#define NL 32
#define NH 64

typedef float f4 __attribute__((ext_vector_type(4)));
typedef uint32_t u32x4 __attribute__((ext_vector_type(4)));
typedef short s16x8 __attribute__((ext_vector_type(8)));

union Frag { s16x8 s; uint32_t u[4]; };

// split x = hi + lo (both bf16, RNE); dropped lo*lo term ~2^-18 rel
__device__ __forceinline__ void split_hl(float x, unsigned short& h, unsigned short& l) {
    __hip_bfloat16 bh = __float2bfloat16(x);
    float hf = __bfloat162float(bh);
    __hip_bfloat16 bl = __float2bfloat16(x - hf);
    h = *reinterpret_cast<unsigned short*>(&bh);
    l = *reinterpret_cast<unsigned short*>(&bl);
}

__device__ __forceinline__ uint32_t pack_split(float x) {
    unsigned short h, l;
    split_hl(x, h, l);
    return (uint32_t)h | ((uint32_t)l << 16);
}

__device__ __forceinline__ f4 mfma16(const Frag& a, const Frag& b, f4 c) {
    return __builtin_amdgcn_mfma_f32_16x16x32_bf16(a.s, b.s, c, 0, 0, 0);
}

// swizzled act address: [row][col] u32, 16B-slot XOR with row&7 (bank-conflict-free)
__device__ __forceinline__ u32x4* actPtr(uint32_t* base, int row, int col) {
    uint32_t byte = ((uint32_t)row << 8) + ((uint32_t)col << 2);
    byte ^= (uint32_t)(row & 7) << 4;
    return (u32x4*)((char*)base + byte);
}

// ---------------------------------------------------------------- encoder ---
__global__ __launch_bounds__(256)
void enc_kernel(const float* __restrict__ x,
                const float* __restrict__ We1, const float* __restrict__ be1,
                const float* __restrict__ We2, const float* __restrict__ be2,
                const float* __restrict__ We3, const float* __restrict__ be3,
                const float* __restrict__ We4, const float* __restrict__ be4,
                float* __restrict__ z)
{
    const int RE = 8;
    __shared__ float xs[RE][512];
    __shared__ float ws[128 * 64];
    __shared__ float h[RE][NH];
    __shared__ float h2s[RE][NH];

    const int t  = threadIdx.x;
    const int r0 = blockIdx.x * RE;

    {
        const f4* xv  = (const f4*)(x + (size_t)r0 * 512);
        f4*       xsv = (f4*)&xs[0][0];
        for (int i = t; i < RE * 512 / 4; i += 256) xsv[i] = xv[i];
    }

    const int j = t & 63;
    const int w = t >> 6;

    float acc0 = be1[j], acc1 = be1[j];
    for (int kc = 0; kc < 512; kc += 128) {
        __syncthreads();
        const f4* wv  = (const f4*)(We1 + (size_t)kc * 64);
        f4*       wsv = (f4*)ws;
        for (int i = t; i < 128 * 64 / 4; i += 256) wsv[i] = wv[i];
        __syncthreads();
        #pragma unroll 8
        for (int k = 0; k < 128; ++k) {
            float wval = ws[k * 64 + j];
            acc0 = fmaf(xs[w][kc + k],     wval, acc0);
            acc1 = fmaf(xs[w + 4][kc + k], wval, acc1);
        }
    }
    acc0 = fmaxf(acc0, 0.f); acc1 = fmaxf(acc1, 0.f);
    __syncthreads();
    h[w][j] = acc0; h[w + 4][j] = acc1;
    __syncthreads();

    acc0 = be2[j]; acc1 = be2[j];
    #pragma unroll
    for (int k = 0; k < 64; ++k) {
        float wval = We2[k * 64 + j];
        acc0 = fmaf(h[w][k],     wval, acc0);
        acc1 = fmaf(h[w + 4][k], wval, acc1);
    }
    acc0 = fmaxf(acc0, 0.f); acc1 = fmaxf(acc1, 0.f);
    h2s[w][j] = acc0; h2s[w + 4][j] = acc1;
    __syncthreads();

    acc0 = be3[j]; acc1 = be3[j];
    #pragma unroll
    for (int k = 0; k < 64; ++k) {
        float wval = We3[k * 64 + j];
        acc0 = fmaf(h2s[w][k],     wval, acc0);
        acc1 = fmaf(h2s[w + 4][k], wval, acc1);
    }
    acc0 = fmaxf(acc0, 0.f); acc1 = fmaxf(acc1, 0.f);
    h[w][j] = acc0; h[w + 4][j] = acc1;
    __syncthreads();

    const int j4  = t & 31;
    const int row = t >> 5;
    float acc = be4[j4];
    #pragma unroll
    for (int k = 0; k < 64; ++k)
        acc = fmaf(h[row][k], We4[k * 32 + j4], acc);
    z[(size_t)r0 * 32 + t] = acc;
}

// ---------------------------------------------------------------- decoder ---
// 512 blocks (1 per unit), 4 waves x 16 private rows, 32 row-iterations.
// Transposed MFMA GEMMs: actN^T = WdN^T @ act(N-1)^T, split-bf16 3-term.
__global__ __launch_bounds__(256, 2)
void dec_kernel(const float* __restrict__ z,
                const float* __restrict__ Wd1, const float* __restrict__ bd1,
                const float* __restrict__ Wd2, const float* __restrict__ bd2,
                const float* __restrict__ Wd3, const float* __restrict__ bd3,
                const float* __restrict__ Wd4, const float* __restrict__ bd4,
                float* __restrict__ out)
{
    __shared__ float w1[NL * NH];          // 8 KB fp32 weights
    __shared__ float w2[NH * NH];          // 16 KB
    __shared__ float w3[NH * NH];          // 16 KB
    __shared__ float bs[3][NH];
    __shared__ float w4s[NH];
    __shared__ uint32_t act[4][2][16 * 64]; // per-wave ping/pong, hi|lo packed, 32 KB

    const int u = blockIdx.x;
    const int t = threadIdx.x;

    // stage weights fp32, coalesced
    {
        const f4* s1 = (const f4*)(Wd1 + (size_t)u * NL * NH);
        f4* d1 = (f4*)w1;
        for (int i = t; i < NL * NH / 4; i += 256) d1[i] = s1[i];
        const f4* s2 = (const f4*)(Wd2 + (size_t)u * NH * NH);
        f4* d2 = (f4*)w2;
        for (int i = t; i < NH * NH / 4; i += 256) d2[i] = s2[i];
        const f4* s3 = (const f4*)(Wd3 + (size_t)u * NH * NH);
        f4* d3 = (f4*)w3;
        for (int i = t; i < NH * NH / 4; i += 256) d3[i] = s3[i];
        if (t < NH) {
            bs[0][t] = bd1[(size_t)u * NH + t];
            bs[1][t] = bd2[(size_t)u * NH + t];
            bs[2][t] = bd3[(size_t)u * NH + t];
            w4s[t]   = Wd4[(size_t)u * NH + t];
        }
    }
    __syncthreads();

    const int w  = t >> 6;
    const int lr = t & 15;          // lane "16-index": batch-row within wave tile
    const int lg = (t & 63) >> 4;   // lane group 0..3: k-block / out-col block
    const float b4 = bd4[u];

    // ---- build W^T A-fragments in registers (held across the whole row loop)
    Frag a1h[4], a1l[4], a2h[4][2], a2l[4][2], a3h[4][2], a3l[4][2];
    #pragma unroll
    for (int mt = 0; mt < 4; ++mt) {
        const int c = lr + 16 * mt;     // out-col
        #pragma unroll
        for (int i = 0; i < 4; ++i) {   // L1: K=32, single k-step
            unsigned short h0, l0, h1, l1;
            split_hl(w1[(lg * 8 + 2 * i)     * NH + c], h0, l0);
            split_hl(w1[(lg * 8 + 2 * i + 1) * NH + c], h1, l1);
            a1h[mt].u[i] = (uint32_t)h0 | ((uint32_t)h1 << 16);
            a1l[mt].u[i] = (uint32_t)l0 | ((uint32_t)l1 << 16);
        }
        #pragma unroll
        for (int ks = 0; ks < 2; ++ks) {
            #pragma unroll
            for (int i = 0; i < 4; ++i) {
                const int k = ks * 32 + lg * 8 + 2 * i;
                unsigned short h0, l0, h1, l1;
                split_hl(w2[k * NH + c],       h0, l0);
                split_hl(w2[(k + 1) * NH + c], h1, l1);
                a2h[mt][ks].u[i] = (uint32_t)h0 | ((uint32_t)h1 << 16);
                a2l[mt][ks].u[i] = (uint32_t)l0 | ((uint32_t)l1 << 16);
                split_hl(w3[k * NH + c],       h0, l0);
                split_hl(w3[(k + 1) * NH + c], h1, l1);
                a3h[mt][ks].u[i] = (uint32_t)h0 | ((uint32_t)h1 << 16);
                a3l[mt][ks].u[i] = (uint32_t)l0 | ((uint32_t)l1 << 16);
            }
        }
    }

    // per-lane Wd4 values: col = 16*mt + lg*4 + r
    f4 wd4v[4];
    #pragma unroll
    for (int mt = 0; mt < 4; ++mt)
        wd4v[mt] = *(const f4*)&w4s[16 * mt + lg * 4];

    uint32_t* bufA = &act[w][0][0];
    uint32_t* bufB = &act[w][1][0];
    const int rl = w * 16 + lr;     // block-local row of this lane

    // prologue z load (iter 0); prefetch pattern inside loop
    f4 zc0 = *(const f4*)&z[(size_t)rl * NL + lg * 8];
    f4 zc1 = *(const f4*)&z[(size_t)rl * NL + lg * 8 + 4];

    for (int it = 0; it < 32; ++it) {
        const int rnext = rl + ((it + 1) & 31) * 64;
        f4 zn0 = *(const f4*)&z[(size_t)rnext * NL + lg * 8];
        f4 zn1 = *(const f4*)&z[(size_t)rnext * NL + lg * 8 + 4];

        // ---- L1: split z into B-fragments
        Frag bh, bl;
        #pragma unroll
        for (int i = 0; i < 4; ++i) {
            float x0 = (i < 2) ? zc0[2 * i]     : zc1[2 * i - 4];
            float x1 = (i < 2) ? zc0[2 * i + 1] : zc1[2 * i - 3];
            unsigned short h0, l0, h1, l1;
            split_hl(x0, h0, l0);
            split_hl(x1, h1, l1);
            bh.u[i] = (uint32_t)h0 | ((uint32_t)h1 << 16);
            bl.u[i] = (uint32_t)l0 | ((uint32_t)l1 << 16);
        }

        f4 acc[4];
        #pragma unroll
        for (int mt = 0; mt < 4; ++mt) {
            acc[mt] = *(const f4*)&bs[0][16 * mt + lg * 4];
            acc[mt] = mfma16(a1h[mt], bh, acc[mt]);
            acc[mt] = mfma16(a1l[mt], bh, acc[mt]);
            acc[mt] = mfma16(a1h[mt], bl, acc[mt]);
        }
        #pragma unroll
        for (int mt = 0; mt < 4; ++mt) {
            u32x4 pk;
            #pragma unroll
            for (int r = 0; r < 4; ++r) pk[r] = pack_split(fmaxf(acc[mt][r], 0.f));
            *actPtr(bufA, lr, 16 * mt + lg * 4) = pk;
        }

        // ---- L2
        #pragma unroll
        for (int mt = 0; mt < 4; ++mt) acc[mt] = *(const f4*)&bs[1][16 * mt + lg * 4];
        #pragma unroll
        for (int ks = 0; ks < 2; ++ks) {
            u32x4 p0 = *actPtr(bufA, lr, ks * 32 + lg * 8);
            u32x4 p1 = *actPtr(bufA, lr, ks * 32 + lg * 8 + 4);
            Frag fh, fl;
            fh.u[0] = __builtin_amdgcn_perm(p0[1], p0[0], 0x05040100u);
            fl.u[0] = __builtin_amdgcn_perm(p0[1], p0[0], 0x07060302u);
            fh.u[1] = __builtin_amdgcn_perm(p0[3], p0[2], 0x05040100u);
            fl.u[1] = __builtin_amdgcn_perm(p0[3], p0[2], 0x07060302u);
            fh.u[2] = __builtin_amdgcn_perm(p1[1], p1[0], 0x05040100u);
            fl.u[2] = __builtin_amdgcn_perm(p1[1], p1[0], 0x07060302u);
            fh.u[3] = __builtin_amdgcn_perm(p1[3], p1[2], 0x05040100u);
            fl.u[3] = __builtin_amdgcn_perm(p1[3], p1[2], 0x07060302u);
            #pragma unroll
            for (int mt = 0; mt < 4; ++mt) {
                acc[mt] = mfma16(a2h[mt][ks], fh, acc[mt]);
                acc[mt] = mfma16(a2l[mt][ks], fh, acc[mt]);
                acc[mt] = mfma16(a2h[mt][ks], fl, acc[mt]);
            }
        }
        #pragma unroll
        for (int mt = 0; mt < 4; ++mt) {
            u32x4 pk;
            #pragma unroll
            for (int r = 0; r < 4; ++r) pk[r] = pack_split(fmaxf(acc[mt][r], 0.f));
            *actPtr(bufB, lr, 16 * mt + lg * 4) = pk;
        }

        // ---- L3
        #pragma unroll
        for (int mt = 0; mt < 4; ++mt) acc[mt] = *(const f4*)&bs[2][16 * mt + lg * 4];
        #pragma unroll
        for (int ks = 0; ks < 2; ++ks) {
            u32x4 p0 = *actPtr(bufB, lr, ks * 32 + lg * 8);
            u32x4 p1 = *actPtr(bufB, lr, ks * 32 + lg * 8 + 4);
            Frag fh, fl;
            fh.u[0] = __builtin_amdgcn_perm(p0[1], p0[0], 0x05040100u);
            fl.u[0] = __builtin_amdgcn_perm(p0[1], p0[0], 0x07060302u);
            fh.u[1] = __builtin_amdgcn_perm(p0[3], p0[2], 0x05040100u);
            fl.u[1] = __builtin_amdgcn_perm(p0[3], p0[2], 0x07060302u);
            fh.u[2] = __builtin_amdgcn_perm(p1[1], p1[0], 0x05040100u);
            fl.u[2] = __builtin_amdgcn_perm(p1[1], p1[0], 0x07060302u);
            fh.u[3] = __builtin_amdgcn_perm(p1[3], p1[2], 0x05040100u);
            fl.u[3] = __builtin_amdgcn_perm(p1[3], p1[2], 0x07060302u);
            #pragma unroll
            for (int mt = 0; mt < 4; ++mt) {
                acc[mt] = mfma16(a3h[mt][ks], fh, acc[mt]);
                acc[mt] = mfma16(a3l[mt][ks], fh, acc[mt]);
                acc[mt] = mfma16(a3h[mt][ks], fl, acc[mt]);
            }
        }

        // ---- L4: per-lane dot over its 16 out-cols, reduce over lane groups
        float part = 0.f;
        #pragma unroll
        for (int mt = 0; mt < 4; ++mt) {
            #pragma unroll
            for (int r = 0; r < 4; ++r)
                part = fmaf(fmaxf(acc[mt][r], 0.f), wd4v[mt][r], part);
        }
        part += __shfl_xor(part, 16, 64);
        part += __shfl_xor(part, 32, 64);
        if (lg == 0)
            out[(size_t)(it * 64 + w * 16 + lr) * NU + u] = part + b4;

        zc0 = zn0; zc1 = zn1;
    }
}

// ----------------------------------------------------------------- launch ---
extern "C" void kernel_launch(void* const* d_in, const int* in_sizes, int n_in,
                              void* d_out, int out_size, void* d_ws, size_t ws_size,
                              hipStream_t stream)
{
    const float* x   = (const float*)d_in[0];
    const float* We1 = (const float*)d_in[1];
    const float* be1 = (const float*)d_in[2];
    const float* We2 = (const float*)d_in[3];
    const float* be2 = (const float*)d_in[4];
    const float* We3 = (const float*)d_in[5];
    const float* be3 = (const float*)d_in[6];
    const float* We4 = (const float*)d_in[7];
    const float* be4 = (const float*)d_in[8];
    const float* Wd1 = (const float*)d_in[9];
    const float* bd1 = (const float*)d_in[10];
    const float* Wd2 = (const float*)d_in[11];
    const float* bd2 = (const float*)d_in[12];
    const float* Wd3 = (const float*)d_in[13];
    const float* bd3 = (const float*)d_in[14];
    const float* Wd4 = (const float*)d_in[15];
    const float* bd4 = (const float*)d_in[16];
    float* out = (float*)d_out;

    float* z = (float*)d_ws;   // NB*NL*4 = 256 KB scratch

    enc_kernel<<<NB / 8, 256, 0, stream>>>(x, We1, be1, We2, be2, We3, be3,
                                           We4, be4, z);
    dec_kernel<<<NU, 256, 0, stream>>>(z, Wd1, bd1, Wd2, bd2,
                                       Wd3, bd3, Wd4, bd4, out);
}

// Round 3
// 88.280 us; speedup vs baseline: 3.4972x; 1.2529x over previous
//
#include <hip/hip_runtime.h>
#include <hip/hip_bf16.h>
#include <stdint.h>

#define NB 2048
#define NU 512
#define NL 32
#define NH 64

typedef float  f4    __attribute__((ext_vector_type(4)));
typedef uint32_t u32x4 __attribute__((ext_vector_type(4)));
typedef short  s16x8 __attribute__((ext_vector_type(8)));

__device__ __forceinline__ f4 mfma16(u32x4 a, u32x4 b, f4 c) {
    return __builtin_amdgcn_mfma_f32_16x16x32_bf16(
        __builtin_bit_cast(s16x8, a), __builtin_bit_cast(s16x8, b), c, 0, 0, 0);
}

// truncation split of pair (we,wo): hi exact (bit-AND), lo = rounded remainder.
__device__ __forceinline__ void splitpk(float we, float wo, uint32_t& hp, uint32_t& lp) {
    uint32_t ue = __float_as_uint(we), uo = __float_as_uint(wo);
    hp = __builtin_amdgcn_perm(uo, ue, 0x07060302u);
    float le = we - __uint_as_float(ue & 0xFFFF0000u);
    float lo = wo - __uint_as_float(uo & 0xFFFF0000u);
    lp = __builtin_amdgcn_perm(__float_as_uint(lo) + 0x8000u,
                               __float_as_uint(le) + 0x8000u, 0x07060302u);
}

// round-to-nearest(ish) single-bf16 pack of a pair
__device__ __forceinline__ uint32_t rpk(float e, float o) {
    return __builtin_amdgcn_perm(__float_as_uint(o) + 0x8000u,
                                 __float_as_uint(e) + 0x8000u, 0x07060302u);
}

// ---------------------------------------------------------------- encoder ---
__global__ __launch_bounds__(256)
void enc_kernel(const float* __restrict__ x,
                const float* __restrict__ We1, const float* __restrict__ be1,
                const float* __restrict__ We2, const float* __restrict__ be2,
                const float* __restrict__ We3, const float* __restrict__ be3,
                const float* __restrict__ We4, const float* __restrict__ be4,
                float* __restrict__ z)
{
    const int RE = 8;
    __shared__ float xs[RE][512];
    __shared__ float ws[128 * 64];
    __shared__ float h[RE][NH];
    __shared__ float h2s[RE][NH];

    const int t  = threadIdx.x;
    const int r0 = blockIdx.x * RE;

    {
        const f4* xv  = (const f4*)(x + (size_t)r0 * 512);
        f4*       xsv = (f4*)&xs[0][0];
        for (int i = t; i < RE * 512 / 4; i += 256) xsv[i] = xv[i];
    }

    const int j = t & 63;
    const int w = t >> 6;

    float acc0 = be1[j], acc1 = be1[j];
    for (int kc = 0; kc < 512; kc += 128) {
        __syncthreads();
        const f4* wv  = (const f4*)(We1 + (size_t)kc * 64);
        f4*       wsv = (f4*)ws;
        for (int i = t; i < 128 * 64 / 4; i += 256) wsv[i] = wv[i];
        __syncthreads();
        #pragma unroll 8
        for (int k = 0; k < 128; ++k) {
            float wval = ws[k * 64 + j];
            acc0 = fmaf(xs[w][kc + k],     wval, acc0);
            acc1 = fmaf(xs[w + 4][kc + k], wval, acc1);
        }
    }
    acc0 = fmaxf(acc0, 0.f); acc1 = fmaxf(acc1, 0.f);
    __syncthreads();
    h[w][j] = acc0; h[w + 4][j] = acc1;
    __syncthreads();

    acc0 = be2[j]; acc1 = be2[j];
    #pragma unroll
    for (int k = 0; k < 64; ++k) {
        float wval = We2[k * 64 + j];
        acc0 = fmaf(h[w][k],     wval, acc0);
        acc1 = fmaf(h[w + 4][k], wval, acc1);
    }
    acc0 = fmaxf(acc0, 0.f); acc1 = fmaxf(acc1, 0.f);
    h2s[w][j] = acc0; h2s[w + 4][j] = acc1;
    __syncthreads();

    acc0 = be3[j]; acc1 = be3[j];
    #pragma unroll
    for (int k = 0; k < 64; ++k) {
        float wval = We3[k * 64 + j];
        acc0 = fmaf(h2s[w][k],     wval, acc0);
        acc1 = fmaf(h2s[w + 4][k], wval, acc1);
    }
    acc0 = fmaxf(acc0, 0.f); acc1 = fmaxf(acc1, 0.f);
    h[w][j] = acc0; h[w + 4][j] = acc1;
    __syncthreads();

    const int j4  = t & 31;
    const int row = t >> 5;
    float acc = be4[j4];
    #pragma unroll
    for (int k = 0; k < 64; ++k)
        acc = fmaf(h[row][k], We4[k * 32 + j4], acc);
    z[(size_t)r0 * 32 + t] = acc;
}

// ---------------------------------------------------------------- decoder ---
// 512 blocks (1/unit), 4 waves x 16 private rows, 32 iters.
// Transposed MFMA GEMMs; weights split-bf16 (register frags); act
// redistribution via ds_bpermute (no LDS round trip).
__global__ __launch_bounds__(256) __attribute__((amdgpu_waves_per_eu(2)))
void dec_kernel(const float* __restrict__ z,
                const float* __restrict__ Wd1, const float* __restrict__ bd1,
                const float* __restrict__ Wd2, const float* __restrict__ bd2,
                const float* __restrict__ Wd3, const float* __restrict__ bd3,
                const float* __restrict__ Wd4, const float* __restrict__ bd4,
                float* __restrict__ out)
{
    __shared__ float w1[NL * NH];     // 8 KB
    __shared__ float w2[NH * NH];     // 16 KB
    __shared__ float w3[NH * NH];     // 16 KB
    __shared__ float bsh[3][NH];
    __shared__ float w4s[NH];

    const int u = blockIdx.x;
    const int t = threadIdx.x;

    // stage weights (coalesced f4)
    {
        const f4* s1 = (const f4*)(Wd1 + (size_t)u * NL * NH);
        f4* d1 = (f4*)w1;
        for (int i = t; i < NL * NH / 4; i += 256) d1[i] = s1[i];
        const f4* s2 = (const f4*)(Wd2 + (size_t)u * NH * NH);
        f4* d2 = (f4*)w2;
        for (int i = t; i < NH * NH / 4; i += 256) d2[i] = s2[i];
        const f4* s3 = (const f4*)(Wd3 + (size_t)u * NH * NH);
        f4* d3 = (f4*)w3;
        for (int i = t; i < NH * NH / 4; i += 256) d3[i] = s3[i];
        if (t < NH) {
            bsh[0][t] = bd1[(size_t)u * NH + t];
            bsh[1][t] = bd2[(size_t)u * NH + t];
            bsh[2][t] = bd3[(size_t)u * NH + t];
            w4s[t]    = Wd4[(size_t)u * NH + t];
        }
    }
    __syncthreads();

    const int w  = t >> 6;          // wave 0..3
    const int lr = t & 15;          // batch-row lane
    const int lg = (t & 63) >> 4;   // lane group 0..3
    const bool hi32 = (t & 32) != 0;
    const float b4 = bd4[u];

    // ---- register A-fragments (W^T), truncation-split hi/lo ----
    u32x4 a1h[4], a1l[4];
    u32x4 a2h[4][2], a2l[4][2], a3h[4][2], a3l[4][2];
    #pragma unroll
    for (int mt = 0; mt < 4; ++mt) {
        const int c = lr + 16 * mt;
        #pragma unroll
        for (int i = 0; i < 4; ++i) {
            uint32_t hp, lp;
            splitpk(w1[(lg * 8 + 2 * i) * NH + c], w1[(lg * 8 + 2 * i + 1) * NH + c], hp, lp);
            a1h[mt][i] = hp; a1l[mt][i] = lp;
        }
        #pragma unroll
        for (int ks = 0; ks < 2; ++ks) {
            #pragma unroll
            for (int i = 0; i < 4; ++i) {
                const int k = ks * 32 + lg * 8 + 2 * i;
                uint32_t hp, lp;
                splitpk(w2[k * NH + c], w2[(k + 1) * NH + c], hp, lp);
                a2h[mt][ks][i] = hp; a2l[mt][ks][i] = lp;
                splitpk(w3[k * NH + c], w3[(k + 1) * NH + c], hp, lp);
                a3h[mt][ks][i] = hp; a3l[mt][ks][i] = lp;
            }
        }
    }

    // biases packed bf16 pairs (exact here: zeros)
    uint32_t bpk1[4][2], bpk2[4][2], bpk3[4][2];
    #pragma unroll
    for (int mt = 0; mt < 4; ++mt) {
        const int c = 16 * mt + lg * 4;
        bpk1[mt][0] = rpk(bsh[0][c], bsh[0][c + 1]);
        bpk1[mt][1] = rpk(bsh[0][c + 2], bsh[0][c + 3]);
        bpk2[mt][0] = rpk(bsh[1][c], bsh[1][c + 1]);
        bpk2[mt][1] = rpk(bsh[1][c + 2], bsh[1][c + 3]);
        bpk3[mt][0] = rpk(bsh[2][c], bsh[2][c + 1]);
        bpk3[mt][1] = rpk(bsh[2][c + 2], bsh[2][c + 3]);
    }

    // bpermute byte indices: source lane = lr + 32*(lg&1) + 16*(i>>1)
    const int idxA = (lr + 32 * (lg & 1)) << 2;
    const int idxB = idxA + 64;

    for (int it = 0; it < 32; ++it) {
        const int row = it * 64 + w * 16 + lr;
        const float* zp = z + (size_t)row * NL + lg * 8;
        f4 z0 = *(const f4*)zp;
        f4 z1 = *(const f4*)(zp + 4);

        // ---- L1 B: split z (3-term keeps z exact) ----
        u32x4 bh, bl;
        {
            uint32_t hp, lp;
            splitpk(z0[0], z0[1], hp, lp); bh[0] = hp; bl[0] = lp;
            splitpk(z0[2], z0[3], hp, lp); bh[1] = hp; bl[1] = lp;
            splitpk(z1[0], z1[1], hp, lp); bh[2] = hp; bl[2] = lp;
            splitpk(z1[2], z1[3], hp, lp); bh[3] = hp; bl[3] = lp;
        }

        f4 acc[4];
        #pragma unroll
        for (int mt = 0; mt < 4; ++mt) {
            acc[mt][0] = __uint_as_float(bpk1[mt][0] << 16);
            acc[mt][1] = __uint_as_float(bpk1[mt][0] & 0xFFFF0000u);
            acc[mt][2] = __uint_as_float(bpk1[mt][1] << 16);
            acc[mt][3] = __uint_as_float(bpk1[mt][1] & 0xFFFF0000u);
            acc[mt] = mfma16(a1h[mt], bh, acc[mt]);
            acc[mt] = mfma16(a1l[mt], bh, acc[mt]);
            acc[mt] = mfma16(a1h[mt], bl, acc[mt]);
        }

        // relu + pack h1 (single bf16)
        uint32_t pk[4][2];
        #pragma unroll
        for (int mt = 0; mt < 4; ++mt) {
            pk[mt][0] = rpk(fmaxf(acc[mt][0], 0.f), fmaxf(acc[mt][1], 0.f));
            pk[mt][1] = rpk(fmaxf(acc[mt][2], 0.f), fmaxf(acc[mt][3], 0.f));
        }

        // ---- L2 ----
        #pragma unroll
        for (int mt = 0; mt < 4; ++mt) {
            acc[mt][0] = __uint_as_float(bpk2[mt][0] << 16);
            acc[mt][1] = __uint_as_float(bpk2[mt][0] & 0xFFFF0000u);
            acc[mt][2] = __uint_as_float(bpk2[mt][1] << 16);
            acc[mt][3] = __uint_as_float(bpk2[mt][1] & 0xFFFF0000u);
        }
        #pragma unroll
        for (int ks = 0; ks < 2; ++ks) {
            u32x4 bf;
            {
                int s0 = __builtin_amdgcn_ds_bpermute(idxA, (int)pk[2 * ks + 0][0]);
                int s1 = __builtin_amdgcn_ds_bpermute(idxA, (int)pk[2 * ks + 1][0]);
                bf[0] = (uint32_t)(hi32 ? s1 : s0);
                int s2 = __builtin_amdgcn_ds_bpermute(idxA, (int)pk[2 * ks + 0][1]);
                int s3 = __builtin_amdgcn_ds_bpermute(idxA, (int)pk[2 * ks + 1][1]);
                bf[1] = (uint32_t)(hi32 ? s3 : s2);
                int s4 = __builtin_amdgcn_ds_bpermute(idxB, (int)pk[2 * ks + 0][0]);
                int s5 = __builtin_amdgcn_ds_bpermute(idxB, (int)pk[2 * ks + 1][0]);
                bf[2] = (uint32_t)(hi32 ? s5 : s4);
                int s6 = __builtin_amdgcn_ds_bpermute(idxB, (int)pk[2 * ks + 0][1]);
                int s7 = __builtin_amdgcn_ds_bpermute(idxB, (int)pk[2 * ks + 1][1]);
                bf[3] = (uint32_t)(hi32 ? s7 : s6);
            }
            #pragma unroll
            for (int mt = 0; mt < 4; ++mt) {
                acc[mt] = mfma16(a2h[mt][ks], bf, acc[mt]);
                acc[mt] = mfma16(a2l[mt][ks], bf, acc[mt]);
            }
        }

        // relu + pack h2
        uint32_t pk2[4][2];
        #pragma unroll
        for (int mt = 0; mt < 4; ++mt) {
            pk2[mt][0] = rpk(fmaxf(acc[mt][0], 0.f), fmaxf(acc[mt][1], 0.f));
            pk2[mt][1] = rpk(fmaxf(acc[mt][2], 0.f), fmaxf(acc[mt][3], 0.f));
        }

        // ---- L3 ----
        #pragma unroll
        for (int mt = 0; mt < 4; ++mt) {
            acc[mt][0] = __uint_as_float(bpk3[mt][0] << 16);
            acc[mt][1] = __uint_as_float(bpk3[mt][0] & 0xFFFF0000u);
            acc[mt][2] = __uint_as_float(bpk3[mt][1] << 16);
            acc[mt][3] = __uint_as_float(bpk3[mt][1] & 0xFFFF0000u);
        }
        #pragma unroll
        for (int ks = 0; ks < 2; ++ks) {
            u32x4 bf;
            {
                int s0 = __builtin_amdgcn_ds_bpermute(idxA, (int)pk2[2 * ks + 0][0]);
                int s1 = __builtin_amdgcn_ds_bpermute(idxA, (int)pk2[2 * ks + 1][0]);
                bf[0] = (uint32_t)(hi32 ? s1 : s0);
                int s2 = __builtin_amdgcn_ds_bpermute(idxA, (int)pk2[2 * ks + 0][1]);
                int s3 = __builtin_amdgcn_ds_bpermute(idxA, (int)pk2[2 * ks + 1][1]);
                bf[1] = (uint32_t)(hi32 ? s3 : s2);
                int s4 = __builtin_amdgcn_ds_bpermute(idxB, (int)pk2[2 * ks + 0][0]);
                int s5 = __builtin_amdgcn_ds_bpermute(idxB, (int)pk2[2 * ks + 1][0]);
                bf[2] = (uint32_t)(hi32 ? s5 : s4);
                int s6 = __builtin_amdgcn_ds_bpermute(idxB, (int)pk2[2 * ks + 0][1]);
                int s7 = __builtin_amdgcn_ds_bpermute(idxB, (int)pk2[2 * ks + 1][1]);
                bf[3] = (uint32_t)(hi32 ? s7 : s6);
            }
            #pragma unroll
            for (int mt = 0; mt < 4; ++mt) {
                acc[mt] = mfma16(a3h[mt][ks], bf, acc[mt]);
                acc[mt] = mfma16(a3l[mt][ks], bf, acc[mt]);
            }
        }

        // ---- L4: fp32 dot with wd4 (h3 never rounded) ----
        float part = 0.f;
        #pragma unroll
        for (int mt = 0; mt < 4; ++mt) {
            f4 wv = *(const f4*)&w4s[16 * mt + lg * 4];
            part = fmaf(fmaxf(acc[mt][0], 0.f), wv[0], part);
            part = fmaf(fmaxf(acc[mt][1], 0.f), wv[1], part);
            part = fmaf(fmaxf(acc[mt][2], 0.f), wv[2], part);
            part = fmaf(fmaxf(acc[mt][3], 0.f), wv[3], part);
        }
        part += __shfl_xor(part, 16);
        part += __shfl_xor(part, 32);
        if ((t & 48) == 0)
            out[(size_t)row * NU + u] = part + b4;
    }
}

// ----------------------------------------------------------------- launch ---
extern "C" void kernel_launch(void* const* d_in, const int* in_sizes, int n_in,
                              void* d_out, int out_size, void* d_ws, size_t ws_size,
                              hipStream_t stream)
{
    const float* x   = (const float*)d_in[0];
    const float* We1 = (const float*)d_in[1];
    const float* be1 = (const float*)d_in[2];
    const float* We2 = (const float*)d_in[3];
    const float* be2 = (const float*)d_in[4];
    const float* We3 = (const float*)d_in[5];
    const float* be3 = (const float*)d_in[6];
    const float* We4 = (const float*)d_in[7];
    const float* be4 = (const float*)d_in[8];
    const float* Wd1 = (const float*)d_in[9];
    const float* bd1 = (const float*)d_in[10];
    const float* Wd2 = (const float*)d_in[11];
    const float* bd2 = (const float*)d_in[12];
    const float* Wd3 = (const float*)d_in[13];
    const float* bd3 = (const float*)d_in[14];
    const float* Wd4 = (const float*)d_in[15];
    const float* bd4 = (const float*)d_in[16];
    float* out = (float*)d_out;

    float* zbuf = (float*)d_ws;   // 256 KB scratch

    enc_kernel<<<NB / 8, 256, 0, stream>>>(x, We1, be1, We2, be2, We3, be3,
                                           We4, be4, zbuf);
    dec_kernel<<<NU, 256, 0, stream>>>(zbuf, Wd1, bd1, Wd2, bd2,
                                       Wd3, bd3, Wd4, bd4, out);
}